// Round 5
// baseline (288.658 us; speedup 1.0000x reference)
//
#include <hip/hip_runtime.h>

typedef unsigned short u16;
typedef unsigned int u32;
typedef _Float16 f16x8 __attribute__((ext_vector_type(8)));
typedef float f32x4 __attribute__((ext_vector_type(4)));

#define LDST 40  // LDS row stride in u16 (80B)

__device__ __forceinline__ u16 f2h(float f) {
  union { _Float16 h; u16 u; } c; c.h = (_Float16)f; return c.u;
}
__device__ __forceinline__ float h2f(u16 v) {
  union { u16 u; _Float16 h; } c; c.u = v; return (float)c.h;
}

__device__ __forceinline__ f32x4 mfma16(f16x8 a, f16x8 b, f32x4 c) {
  return __builtin_amdgcn_mfma_f32_16x16x32_f16(a, b, c, 0, 0, 0);
}

// 8 contiguous fp32 -> 8 fp16 (u16)
__device__ __forceinline__ void ld8f(const float* s, u16* o) {
  float4 a = *(const float4*)s;
  float4 b = *(const float4*)(s + 4);
  o[0] = f2h(a.x); o[1] = f2h(a.y); o[2] = f2h(a.z); o[3] = f2h(a.w);
  o[4] = f2h(b.x); o[5] = f2h(b.y); o[6] = f2h(b.z); o[7] = f2h(b.w);
}

// NT tile core: C[BM,BN] += A[BM,K] * B[BN,K]^T, K-contiguous operands (lda/ldb in elems).
// AF32/BF32: operand is fp32, converted to fp16 during LDS staging (else fp16-in-u16).
// BM=TM*32, BN=TN*32 (2x2 waves, TMxTN 16x16 mfma tiles per wave). 256 threads.
template<int TM, int TN, bool AF32, bool BF32>
__device__ __forceinline__ void gemm_core(const void* Ab, int lda, const void* Bb, int ldb,
                                          int ksteps, u16* sA, u16* sB, f32x4 acc[TM][TN]) {
  const int t = threadIdx.x;
  const int lane = t & 63, wave = t >> 6;
  const int wm = wave >> 1, wn = wave & 1;
  const int m16 = lane & 15, q4 = lane >> 4;
  constexpr int BM = TM * 32, BN = TN * 32;
  size_t ko = 0;

  for (int kt = 0; kt < ksteps; ++kt) {
    __syncthreads();
#pragma unroll
    for (int p = 0; p < BM / 64; ++p) {
      int flat = (p * 256 + t) * 8;
      int row = flat >> 5, col = flat & 31;
      u16 o[8];
      if constexpr (AF32) ld8f((const float*)Ab + (size_t)row * lda + ko + col, o);
      else *(int4*)o = *(const int4*)((const u16*)Ab + (size_t)row * lda + ko + col);
      *(int4*)&sA[row * LDST + col] = *(int4*)o;
    }
#pragma unroll
    for (int p = 0; p < BN / 64; ++p) {
      int flat = (p * 256 + t) * 8;
      int row = flat >> 5, col = flat & 31;
      u16 o[8];
      if constexpr (BF32) ld8f((const float*)Bb + (size_t)row * ldb + ko + col, o);
      else *(int4*)o = *(const int4*)((const u16*)Bb + (size_t)row * ldb + ko + col);
      *(int4*)&sB[row * LDST + col] = *(int4*)o;
    }
    __syncthreads();

    f16x8 af[TM], bv[TN];
#pragma unroll
    for (int i = 0; i < TM; ++i)
      af[i] = *(const f16x8*)&sA[(wm * TM * 16 + i * 16 + m16) * LDST + q4 * 8];
#pragma unroll
    for (int j = 0; j < TN; ++j)
      bv[j] = *(const f16x8*)&sB[(wn * TN * 16 + j * 16 + m16) * LDST + q4 * 8];
#pragma unroll
    for (int i = 0; i < TM; ++i)
#pragma unroll
      for (int j = 0; j < TN; ++j)
        acc[i][j] = mfma16(af[i], bv[j], acc[i][j]);

    ko += 32;
  }
}

// fused prep, block roles:
// [0,4096):    xhT[b][n][o] = fp16(x[b][o][n])  (64x64 LDS transpose tiles)
// [4096,4608): qs[row] = sum_n q[row][n]
// [4608,4864): vwT[o][x] = fp16(vw[x][o])
// [4864,4992): kwh = fp16(kw)
// 4992:        beta = 0
__global__ __launch_bounds__(256) void prep_kernel(const float* __restrict__ x, u16* __restrict__ xhT,
                                                   const float* __restrict__ q, float* __restrict__ qs,
                                                   const float* __restrict__ vw, u16* __restrict__ vwT,
                                                   const float* __restrict__ kw, u16* __restrict__ kwh,
                                                   float* __restrict__ beta) {
  int blk = blockIdx.x, t = threadIdx.x;
  if (blk < 4096) {
    __shared__ u16 sT[64 * 72];
    int b = blk >> 9, rem = blk & 511, nt = rem & 63, ot = rem >> 6;
    const float* xb = x + (size_t)b * 2097152 + (size_t)(ot * 64) * 4096 + nt * 64;
#pragma unroll
    for (int p = 0; p < 4; ++p) {
      int idx = p * 256 + t;
      int r = idx >> 4, c4 = (idx & 15) * 4;
      float4 v = *(const float4*)&xb[(size_t)r * 4096 + c4];
      u16 o4[4] = {f2h(v.x), f2h(v.y), f2h(v.z), f2h(v.w)};
      *(uint2*)&sT[r * 72 + c4] = *(uint2*)o4;
    }
    __syncthreads();
#pragma unroll
    for (int p = 0; p < 2; ++p) {
      int idx = p * 256 + t;
      int r2 = idx >> 3, c8 = (idx & 7) * 8;
      u16 o[8];
#pragma unroll
      for (int e = 0; e < 8; ++e) o[e] = sT[(c8 + e) * 72 + r2];
      *(int4*)&xhT[(size_t)b * 2097152 + (size_t)(nt * 64 + r2) * 512 + ot * 64 + c8] = *(int4*)o;
    }
  } else if (blk < 4608) {
    int row = blk - 4096;
    float s = 0.f;
#pragma unroll
    for (int p = 0; p < 4; ++p) {
      float4 v = *(const float4*)&q[(size_t)row * 4096 + p * 1024 + t * 4];
      s += v.x + v.y + v.z + v.w;
    }
    for (int off = 32; off; off >>= 1) s += __shfl_xor(s, off);
    __shared__ float wsum[4];
    if ((t & 63) == 0) wsum[t >> 6] = s;
    __syncthreads();
    if (t == 0) qs[row] = wsum[0] + wsum[1] + wsum[2] + wsum[3];
  } else if (blk < 4864) {
    __shared__ u16 sV[32 * 33];
    int rel = blk - 4608;
    int bx = rel & 15, by = rel >> 4;
#pragma unroll
    for (int p = 0; p < 4; ++p) {
      int idx = p * 256 + t; int r = idx >> 5, c = idx & 31;
      sV[r * 33 + c] = f2h(vw[(size_t)(by * 32 + r) * 512 + bx * 32 + c]);
    }
    __syncthreads();
#pragma unroll
    for (int p = 0; p < 4; ++p) {
      int idx = p * 256 + t; int r = idx >> 5, c = idx & 31;
      vwT[(size_t)(bx * 32 + r) * 512 + by * 32 + c] = sV[c * 33 + r];
    }
  } else if (blk < 4992) {
    size_t i = ((size_t)(blk - 4864) * 256 + t) * 8;
    u16 o[8];
    ld8f(kw + i, o);
    *(int4*)&kwh[i] = *(int4*)o;
  } else {
    for (int i = t; i < 4096; i += 256) beta[i] = 0.f;
  }
}

// Sh[b][y][o] = fp16( sum_n q[y,n]*x[(b,o),n] ); 64x64 tiles, K=4096, fp32 operands staged->fp16
__global__ __launch_bounds__(256) void sgemm_kernel(const float* __restrict__ q, const float* __restrict__ x,
                                                    u16* __restrict__ Sh) {
  __shared__ u16 sA[64 * LDST], sB[64 * LDST];
  int rt = blockIdx.x, jt = blockIdx.y;
  f32x4 acc[2][2];
#pragma unroll
  for (int i = 0; i < 2; ++i)
#pragma unroll
    for (int j = 0; j < 2; ++j) acc[i][j] = (f32x4){0.f, 0.f, 0.f, 0.f};
  gemm_core<2, 2, true, true>(q + (size_t)jt * 64 * 4096, 4096,
                              x + (size_t)rt * 64 * 4096, 4096, 128, sA, sB, acc);

  const int t = threadIdx.x, lane = t & 63, wave = t >> 6;
  const int wm = wave >> 1, wn = wave & 1, m16 = lane & 15, q4 = lane >> 4;
  int b = (rt * 64) >> 9, o0 = (rt * 64) & 511;
  u16* Ob = Sh + (size_t)b * 262144;
#pragma unroll
  for (int i = 0; i < 2; ++i)
#pragma unroll
    for (int j = 0; j < 2; ++j)
#pragma unroll
      for (int r = 0; r < 4; ++r) {
        int y = jt * 64 + wm * 32 + i * 16 + q4 * 4 + r;
        int o = o0 + wn * 32 + j * 16 + m16;
        Ob[(size_t)y * 512 + o] = f2h(acc[i][j][r]);
      }
}

// E[b,x,y] = sum_o kw[x,o] * Sh[b][y][o]
__global__ __launch_bounds__(256) void egemm_kernel(const u16* __restrict__ kwh, const u16* __restrict__ Sh,
                                                    float* __restrict__ E) {
  __shared__ u16 sA[64 * LDST], sB[64 * LDST];
  int xt = blockIdx.x >> 3, yt = blockIdx.x & 7, b = blockIdx.y;
  f32x4 acc[2][2];
#pragma unroll
  for (int i = 0; i < 2; ++i)
#pragma unroll
    for (int j = 0; j < 2; ++j) acc[i][j] = (f32x4){0.f, 0.f, 0.f, 0.f};
  gemm_core<2, 2, false, false>(kwh + (size_t)xt * 64 * 512, 512,
                                Sh + (size_t)b * 262144 + (size_t)yt * 64 * 512, 512, 16, sA, sB, acc);

  const int t = threadIdx.x, lane = t & 63, wave = t >> 6;
  const int wm = wave >> 1, wn = wave & 1, m16 = lane & 15, q4 = lane >> 4;
  float* O = E + ((size_t)b * 512 + xt * 64) * 512 + yt * 64;
#pragma unroll
  for (int i = 0; i < 2; ++i)
#pragma unroll
    for (int j = 0; j < 2; ++j)
#pragma unroll
      for (int r = 0; r < 4; ++r) {
        int row = wm * 32 + i * 16 + q4 * 4 + r;
        int col = wn * 32 + j * 16 + m16;
        O[(size_t)row * 512 + col] = acc[i][j][r];
      }
}

// softmax over y of (E[b,x,y]+kb[x]*qs[y]); writes attT[b][y][x] fp16; beta[b][y] += sum_x att*vb[x]
__global__ __launch_bounds__(256) void softmax_kernel(const float* __restrict__ E, const float* __restrict__ qs,
                                                      const float* __restrict__ kb, const float* __restrict__ vb,
                                                      u16* __restrict__ attT, float* __restrict__ beta) {
  __shared__ float sE[16 * 516];
  __shared__ float sM[16], sS[16];
  int i0 = blockIdx.x * 16, b = blockIdx.y, t = threadIdx.x;
  const float* Eb = E + ((size_t)b * 512 + i0) * 512;
  for (int ch = 0; ch < 32; ++ch) {
    int idx = ch * 256 + t;
    int row = idx >> 9, col = idx & 511;
    sE[row * 516 + col] = Eb[(size_t)row * 512 + col] + kb[i0 + row] * qs[col];
  }
  __syncthreads();
  {
    int row = t >> 4, sub = t & 15;
    float mx = -1e30f;
    for (int ii = 0; ii < 32; ++ii) mx = fmaxf(mx, sE[row * 516 + sub + ii * 16]);
    for (int off = 8; off; off >>= 1) mx = fmaxf(mx, __shfl_xor(mx, off));
    float sm = 0.f;
    for (int ii = 0; ii < 32; ++ii) sm += __expf(sE[row * 516 + sub + ii * 16] - mx);
    for (int off = 8; off; off >>= 1) sm += __shfl_xor(sm, off);
    if (sub == 0) { sM[row] = mx; sS[row] = 1.f / sm; }
  }
  __syncthreads();
  float vbr = vb[i0 + (t & 15)];
  u16* Ob = attT + (size_t)b * 262144;
  for (int ch = 0; ch < 32; ++ch) {
    int idx = ch * 256 + t;
    int r = idx & 15, j = idx >> 4;
    float a = __expf(sE[r * 516 + j] - sM[r]) * sS[r];
    Ob[(size_t)j * 512 + i0 + r] = f2h(a);
    float part = a * vbr;
    for (int off = 8; off; off >>= 1) part += __shfl_xor(part, off);
    if (r == 0) atomicAdd(&beta[b * 512 + j], part);
  }
}

// W[b][c][o] = sum_x attT[b][c][x] * vwT[o][x]
__global__ __launch_bounds__(256) void wgemm_kernel(const u16* __restrict__ attT, const u16* __restrict__ vwT,
                                                    u16* __restrict__ W) {
  __shared__ u16 sA[64 * LDST], sB[64 * LDST];
  int ct = blockIdx.x >> 3, ot = blockIdx.x & 7, b = blockIdx.y;
  f32x4 acc[2][2];
#pragma unroll
  for (int i = 0; i < 2; ++i)
#pragma unroll
    for (int j = 0; j < 2; ++j) acc[i][j] = (f32x4){0.f, 0.f, 0.f, 0.f};
  gemm_core<2, 2, false, false>(attT + (size_t)b * 262144 + (size_t)ct * 64 * 512, 512,
                                vwT + (size_t)ot * 64 * 512, 512, 16, sA, sB, acc);

  const int t = threadIdx.x, lane = t & 63, wave = t >> 6;
  const int wm = wave >> 1, wn = wave & 1, m16 = lane & 15, q4 = lane >> 4;
  u16* O = W + (size_t)b * 262144 + (size_t)(ct * 64) * 512 + ot * 64;
#pragma unroll
  for (int i = 0; i < 2; ++i)
#pragma unroll
    for (int j = 0; j < 2; ++j)
#pragma unroll
      for (int r = 0; r < 4; ++r) {
        int row = wm * 32 + i * 16 + q4 * 4 + r;
        int col = wn * 32 + j * 16 + m16;
        O[(size_t)row * 512 + col] = f2h(acc[i][j][r]);
      }
}

// out[b,c,n] = gamma*(sum_o W[b,c,o]*xhT[b,n,o] + beta[b,c]) + x[b,c,n]  (plain NT via xhT)
__global__ __launch_bounds__(256) void outgemm_kernel(const u16* __restrict__ W, const u16* __restrict__ xhT,
                                                      const float* __restrict__ x, const float* __restrict__ beta,
                                                      const float* __restrict__ gm, float* __restrict__ out) {
  __shared__ u16 sA[128 * LDST], sB[128 * LDST];
  int nt = blockIdx.x, ct = blockIdx.y, b = blockIdx.z;
  f32x4 acc[4][4];
#pragma unroll
  for (int i = 0; i < 4; ++i)
#pragma unroll
    for (int j = 0; j < 4; ++j) acc[i][j] = (f32x4){0.f, 0.f, 0.f, 0.f};
  gemm_core<4, 4, false, false>(W + (size_t)b * 262144 + (size_t)ct * 128 * 512, 512,
                                xhT + (size_t)b * 2097152 + (size_t)nt * 128 * 512, 512, 16, sA, sB, acc);

  const int t = threadIdx.x, lane = t & 63, wave = t >> 6;
  const int wm = wave >> 1, wn = wave & 1, m16 = lane & 15, q4 = lane >> 4;
  float g = gm[0];
#pragma unroll
  for (int i = 0; i < 4; ++i)
#pragma unroll
    for (int j = 0; j < 4; ++j)
#pragma unroll
      for (int r = 0; r < 4; ++r) {
        int c = ct * 128 + wm * 64 + i * 16 + q4 * 4 + r;
        int n = nt * 128 + wn * 64 + j * 16 + m16;
        size_t idx = (size_t)b * 2097152 + (size_t)c * 4096 + n;
        out[idx] = g * (acc[i][j][r] + beta[b * 512 + c]) + x[idx];
      }
}

extern "C" void kernel_launch(void* const* d_in, const int* in_sizes, int n_in,
                              void* d_out, int out_size, void* d_ws, size_t ws_size,
                              hipStream_t stream) {
  const float* x  = (const float*)d_in[0];
  const float* pq = (const float*)d_in[1];
  const float* kw = (const float*)d_in[2];
  const float* kb = (const float*)d_in[3];
  const float* vw = (const float*)d_in[4];
  const float* vb = (const float*)d_in[5];
  const float* gm = (const float*)d_in[6];
  float* out = (float*)d_out;

  // workspace: 49 MB + 20 KB (<= 53 MB proven)
  char* ws = (char*)d_ws;
  u16*   xhT  = (u16*)(ws);                            // [0,32M)  fp16 x^T per batch, live to end
  u16*   Sh   = (u16*)(ws + (32ull << 20));            // [32,36M) reused as W after egemm
  u16*   W    = (u16*)(ws + (32ull << 20));
  float* E    = (float*)(ws + (36ull << 20));          // [36,44M) fp32
  u16*   attT = (u16*)(ws + (44ull << 20));            // [44,48M)
  u16*   kwh  = (u16*)(ws + (48ull << 20));            // 512K
  u16*   vwT  = (u16*)(ws + (48ull << 20) + 524288);   // 512K
  char*  sm   = ws + (49ull << 20);
  float* qs   = (float*)(sm);                          // 2K
  float* beta = (float*)(sm + 4096);                   // 16K

  prep_kernel<<<dim3(4993), 256, 0, stream>>>(x, xhT, pq, qs, vw, vwT, kw, kwh, beta);
  sgemm_kernel<<<dim3(64, 8), 256, 0, stream>>>(pq, x, Sh);
  egemm_kernel<<<dim3(64, 8), 256, 0, stream>>>(kwh, Sh, E);
  softmax_kernel<<<dim3(32, 8), 256, 0, stream>>>(E, qs, kb, vb, attT, beta);
  wgemm_kernel<<<dim3(64, 8), 256, 0, stream>>>(attT, vwT, W);
  outgemm_kernel<<<dim3(32, 4, 8), 256, 0, stream>>>(W, xhT, x, beta, gm, out);
}